// Round 1
// baseline (487.700 us; speedup 1.0000x reference)
//
#include <hip/hip_runtime.h>
#include <math.h>

#define B_   8
#define C_   256
#define N_   4096
#define H_   4
#define D_   64
#define KVC_ 512

__device__ __forceinline__ float waveMax(float x) {
#pragma unroll
  for (int o = 32; o > 0; o >>= 1) x = fmaxf(x, __shfl_down(x, o));
  return x;
}
__device__ __forceinline__ float waveSum(float x) {
#pragma unroll
  for (int o = 32; o > 0; o >>= 1) x += __shfl_down(x, o);
  return x;
}

// C[b] = (A[b] (MxK, row-major) * B[b] (KxN, row-major) + bias[m]) * scale
// sA==0 -> A shared across batch. N is also the leading dim of B and C.
__global__ __launch_bounds__(256, 2) void gemm_nn(
    const float* __restrict__ A, long long sA,
    const float* __restrict__ Bm, long long sB,
    float* __restrict__ Cm, long long sC,
    const float* __restrict__ bias, float scale,
    int M, int K, int N) {
  __shared__ float As[16][68];  // [k][m]
  __shared__ float Bs[16][68];  // [k][n]
  const int b = blockIdx.z;
  const float* Ab = A + (long long)b * sA;
  const float* Bb = Bm + (long long)b * sB;
  float* Cb = Cm + (long long)b * sC;
  const int m0 = blockIdx.y * 64;
  const int n0 = blockIdx.x * 64;
  const int tid = threadIdx.y * 16 + threadIdx.x;
  float acc[4][4] = {};
  for (int k0 = 0; k0 < K; k0 += 16) {
#pragma unroll
    for (int i = 0; i < 4; i++) {
      int idx = tid + i * 256;        // 0..1023 over 64x16 A tile
      int r = idx >> 4, c = idx & 15;
      As[c][r] = Ab[(long long)(m0 + r) * K + (k0 + c)];
    }
#pragma unroll
    for (int i = 0; i < 4; i++) {
      int idx = tid + i * 256;        // 0..1023 over 16x64 B tile
      int r = idx >> 6, c = idx & 63;
      Bs[r][c] = Bb[(long long)(k0 + r) * N + (n0 + c)];
    }
    __syncthreads();
#pragma unroll
    for (int k = 0; k < 16; k++) {
      float a0[4], b0[4];
#pragma unroll
      for (int i = 0; i < 4; i++) a0[i] = As[k][threadIdx.y * 4 + i];
#pragma unroll
      for (int j = 0; j < 4; j++) b0[j] = Bs[k][threadIdx.x * 4 + j];
#pragma unroll
      for (int i = 0; i < 4; i++)
#pragma unroll
        for (int j = 0; j < 4; j++) acc[i][j] = fmaf(a0[i], b0[j], acc[i][j]);
    }
    __syncthreads();
  }
#pragma unroll
  for (int i = 0; i < 4; i++) {
    int m = m0 + threadIdx.y * 4 + i;
    float bi = bias ? bias[m] : 0.0f;
#pragma unroll
    for (int j = 0; j < 4; j++) {
      int n = n0 + threadIdx.x * 4 + j;
      Cb[(long long)m * N + n] = (acc[i][j] + bi) * scale;
    }
  }
}

// ctx[b][m][n] += sum_{k in this split's chunk} A[b][m][k] * Bt[b][n][k]
// ctx leading dim = C_ (256). grid.z = B_ * nsplit.
__global__ __launch_bounds__(256, 2) void gemm_nt_atomic(
    const float* __restrict__ A, long long sA,
    const float* __restrict__ Bt, long long sB,
    float* __restrict__ Cm, long long sC,
    int K, int ldAB, int nsplit) {
  __shared__ float As[16][68];  // [k][m]
  __shared__ float Bs[16][68];  // [k][n]
  const int bz = blockIdx.z;
  const int b = bz / nsplit;
  const int sp = bz % nsplit;
  const int kchunk = K / nsplit;
  const int kbeg = sp * kchunk;
  const float* Ab = A + (long long)b * sA;
  const float* Bb = Bt + (long long)b * sB;
  float* Cb = Cm + (long long)b * sC;
  const int m0 = blockIdx.y * 64;
  const int n0 = blockIdx.x * 64;
  const int tid = threadIdx.y * 16 + threadIdx.x;
  float acc[4][4] = {};
  for (int k0 = kbeg; k0 < kbeg + kchunk; k0 += 16) {
#pragma unroll
    for (int i = 0; i < 4; i++) {
      int idx = tid + i * 256;
      int r = idx >> 4, c = idx & 15;
      As[c][r] = Ab[(long long)(m0 + r) * ldAB + (k0 + c)];
      Bs[c][r] = Bb[(long long)(n0 + r) * ldAB + (k0 + c)];
    }
    __syncthreads();
#pragma unroll
    for (int k = 0; k < 16; k++) {
      float a0[4], b0[4];
#pragma unroll
      for (int i = 0; i < 4; i++) a0[i] = As[k][threadIdx.y * 4 + i];
#pragma unroll
      for (int j = 0; j < 4; j++) b0[j] = Bs[k][threadIdx.x * 4 + j];
#pragma unroll
      for (int i = 0; i < 4; i++)
#pragma unroll
        for (int j = 0; j < 4; j++) acc[i][j] = fmaf(a0[i], b0[j], acc[i][j]);
    }
    __syncthreads();
  }
#pragma unroll
  for (int i = 0; i < 4; i++) {
    int m = m0 + threadIdx.y * 4 + i;
#pragma unroll
    for (int j = 0; j < 4; j++) {
      int n = n0 + threadIdx.x * 4 + j;
      atomicAdd(&Cb[(long long)m * C_ + n], acc[i][j]);
    }
  }
}

// softmax over the 64 channels within a head, for each (b, h, n). In-place.
__global__ __launch_bounds__(256) void softmax_d(float* __restrict__ Q) {
  int g = blockIdx.x * 256 + threadIdx.x;   // 0 .. B_*H_*N_-1
  int n = g & (N_ - 1);
  int h = (g >> 12) & (H_ - 1);
  int b = g >> 14;
  float* base = Q + ((long long)b * C_ + h * D_) * N_ + n;
  float v[D_];
  float mx = -1e30f;
#pragma unroll
  for (int i = 0; i < D_; i++) {
    v[i] = base[(long long)i * N_];
    mx = fmaxf(mx, v[i]);
  }
  float s = 0.0f;
#pragma unroll
  for (int i = 0; i < D_; i++) {
    v[i] = __expf(v[i] - mx);
    s += v[i];
  }
  float inv = 1.0f / s;
#pragma unroll
  for (int i = 0; i < D_; i++) base[(long long)i * N_] = v[i] * inv;
}

// softmax over the N_=4096 row elements of K (= first C_ rows of each KV batch).
// One block per (b, c). In-place.
__global__ __launch_bounds__(256) void softmax_n(float* __restrict__ KV) {
  int b = blockIdx.x / C_;
  int c = blockIdx.x % C_;
  float* row = KV + ((long long)b * KVC_ + c) * N_;
  int t = threadIdx.x;
  int lane = t & 63, wv = t >> 6;
  __shared__ float smax[4];
  __shared__ float ssum[4];

  float v[16];
  float mx = -1e30f;
#pragma unroll
  for (int i = 0; i < 16; i++) {
    v[i] = row[t + i * 256];
    mx = fmaxf(mx, v[i]);
  }
  mx = waveMax(mx);
  if (lane == 0) smax[wv] = mx;
  __syncthreads();
  mx = fmaxf(fmaxf(smax[0], smax[1]), fmaxf(smax[2], smax[3]));

  float s = 0.0f;
#pragma unroll
  for (int i = 0; i < 16; i++) {
    v[i] = __expf(v[i] - mx);
    s += v[i];
  }
  s = waveSum(s);
  if (lane == 0) ssum[wv] = s;
  __syncthreads();
  float inv = 1.0f / (ssum[0] + ssum[1] + ssum[2] + ssum[3]);
#pragma unroll
  for (int i = 0; i < 16; i++) row[t + i * 256] = v[i] * inv;
}

extern "C" void kernel_launch(void* const* d_in, const int* in_sizes, int n_in,
                              void* d_out, int out_size, void* d_ws, size_t ws_size,
                              hipStream_t stream) {
  const float* x     = (const float*)d_in[0];
  const float* cproj = (const float*)d_in[1];
  const float* wq    = (const float*)d_in[2];
  const float* bq    = (const float*)d_in[3];
  const float* wkv   = (const float*)d_in[4];
  const float* bkv   = (const float*)d_in[5];
  const float* wo    = (const float*)d_in[6];
  const float* bo    = (const float*)d_in[7];
  float* out = (float*)d_out;

  // Workspace: Q (B*C*N) | KV (B*512*N) | ctx (B*C*C) | ctx2 (B*C*C) ~= 100 MiB
  float* Q    = (float*)d_ws;
  float* KV   = Q + (long long)B_ * C_ * N_;
  float* ctx  = KV + (long long)B_ * KVC_ * N_;
  float* ctx2 = ctx + (long long)B_ * C_ * C_;

  dim3 blk(16, 16);
  const float scale = 0.25f;  // 256^-0.25

  // 1) Q = (wq @ x + bq) * scale
  gemm_nn<<<dim3(N_ / 64, C_ / 64, B_), blk, 0, stream>>>(
      wq, 0, x, (long long)C_ * N_, Q, (long long)C_ * N_, bq, scale, C_, C_, N_);
  // 2) KV = wkv @ cproj + bkv   (K = rows 0..255, V = rows 256..511 per batch)
  gemm_nn<<<dim3(N_ / 64, KVC_ / 64, B_), blk, 0, stream>>>(
      wkv, 0, cproj, (long long)C_ * N_, KV, (long long)KVC_ * N_, bkv, 1.0f, KVC_, C_, N_);
  // 3) q = softmax over d (in-place on Q)
  softmax_d<<<(B_ * H_ * N_) / 256, 256, 0, stream>>>(Q);
  // 4) k = softmax over N (in-place on K rows of KV)
  softmax_n<<<B_ * C_, 256, 0, stream>>>(KV);
  // 5) context = k @ V^T  (K-split with atomics; zero first)
  hipMemsetAsync(ctx, 0, (size_t)B_ * C_ * C_ * sizeof(float), stream);
  const int NSPLIT = 8;
  gemm_nt_atomic<<<dim3(C_ / 64, C_ / 64, B_ * NSPLIT), blk, 0, stream>>>(
      KV, (long long)KVC_ * N_, KV + (long long)C_ * N_, (long long)KVC_ * N_,
      ctx, (long long)C_ * C_, N_, N_, NSPLIT);
  // 6) ctx2 = wo @ context   (fuses the output projection into a 256x256 GEMM)
  gemm_nn<<<dim3(C_ / 64, C_ / 64, B_), blk, 0, stream>>>(
      wo, 0, ctx, (long long)C_ * C_, ctx2, (long long)C_ * C_, nullptr, 1.0f, C_, C_, C_);
  // 7) out = ctx2 @ q + bo
  gemm_nn<<<dim3(N_ / 64, C_ / 64, B_), blk, 0, stream>>>(
      ctx2, (long long)C_ * C_, Q, (long long)C_ * N_, out, (long long)C_ * N_, bo, 1.0f, C_, C_, N_);
}

// Round 2
// 216.758 us; speedup vs baseline: 2.2500x; 2.2500x over previous
//
#include <hip/hip_runtime.h>

#define B_ 8
#define C_ 256
#define N_ 4096
#define H_ 4
#define KVC_ 512
#define NSPLIT 8

typedef float f32x4 __attribute__((ext_vector_type(4)));
typedef __bf16 bf16x8 __attribute__((ext_vector_type(8)));
typedef unsigned short u16x8 __attribute__((ext_vector_type(8)));
typedef unsigned short u16x4 __attribute__((ext_vector_type(4)));

union BU8 { u16x8 u; bf16x8 b; };

__device__ __forceinline__ unsigned short f2bf(float f) {
  unsigned u = __float_as_uint(f);
  u += 0x7fff + ((u >> 16) & 1);   // RNE; inputs are finite/no-NaN
  return (unsigned short)(u >> 16);
}

__device__ __forceinline__ f32x4 mfma16(bf16x8 a, bf16x8 b, f32x4 c) {
  return __builtin_amdgcn_mfma_f32_16x16x32_bf16(a, b, c, 0, 0, 0);
}

// ---------------------------------------------------------------------------
// G1: qT[b][n][m] = softmax_d((wq @ x + bq) * 0.25), written bf16 transposed.
// M-tile = 256 (full C) x N-tile 64; wave w owns cols w*16..w*16+15, all rows.
// Softmax over each head's 64 rows is in-register: 16 local vals + shfl_xor(16,32).
__global__ __launch_bounds__(256) void qproj_softmax(
    const float* __restrict__ wq, const float* __restrict__ x,
    const float* __restrict__ bq, unsigned short* __restrict__ qT) {
  __shared__ unsigned short As[256][40];  // [m][k] pad->40 (80B rows, 16B aligned)
  __shared__ unsigned short Bs[32][68];   // [k][n] pad->68
  __shared__ float bql[C_];
  const int b = blockIdx.z;
  const int n0 = blockIdx.x * 64;
  const int tid = threadIdx.x;
  const int lane = tid & 63, w = tid >> 6;
  const float* xb = x + (size_t)b * C_ * N_;

  bql[tid] = bq[tid];

  f32x4 acc[16];
#pragma unroll
  for (int i = 0; i < 16; i++) acc[i] = (f32x4){0.f, 0.f, 0.f, 0.f};

  const int colL = lane & 15, kq = lane >> 4;
  for (int kc = 0; kc < C_; kc += 32) {
    __syncthreads();
    // stage A: wq[0..255][kc..kc+31] fp32 -> bf16
#pragma unroll
    for (int i = 0; i < 8; i++) {
      int r = i * 32 + (tid >> 3), c = (tid & 7) * 4;
      float4 v = *(const float4*)&wq[r * C_ + kc + c];
      *(u16x4*)&As[r][c] = (u16x4){f2bf(v.x), f2bf(v.y), f2bf(v.z), f2bf(v.w)};
    }
    // stage B: x[kc..kc+31][n0..n0+63]
#pragma unroll
    for (int i = 0; i < 2; i++) {
      int r = i * 16 + (tid >> 4), c = (tid & 15) * 4;
      float4 v = *(const float4*)&xb[(size_t)(kc + r) * N_ + n0 + c];
      *(u16x4*)&Bs[r][c] = (u16x4){f2bf(v.x), f2bf(v.y), f2bf(v.z), f2bf(v.w)};
    }
    __syncthreads();

    BU8 bu;
#pragma unroll
    for (int j = 0; j < 8; j++) bu.u[j] = Bs[kq * 8 + j][w * 16 + colL];
    bf16x8 bf = bu.b;
#pragma unroll
    for (int mt = 0; mt < 16; mt++) {
      bf16x8 af = *(const bf16x8*)&As[mt * 16 + colL][kq * 8];
      acc[mt] = mfma16(af, bf, acc[mt]);
    }
  }

  // epilogue: bias+scale, per-head softmax over 64 rows, write qT bf16
  const int quad = lane >> 4;
  const int n = n0 + w * 16 + colL;
  unsigned short* qbase = qT + ((size_t)b * N_ + n) * C_;
#pragma unroll
  for (int h = 0; h < H_; h++) {
    float v[16];
    float mx = -1e30f;
#pragma unroll
    for (int i = 0; i < 4; i++) {
      int mt = 4 * h + i;
#pragma unroll
      for (int r = 0; r < 4; r++) {
        int m = mt * 16 + quad * 4 + r;
        float val = (acc[mt][r] + bql[m]) * 0.25f;
        v[i * 4 + r] = val;
        mx = fmaxf(mx, val);
      }
    }
    mx = fmaxf(mx, __shfl_xor(mx, 16));
    mx = fmaxf(mx, __shfl_xor(mx, 32));
    float s = 0.f;
#pragma unroll
    for (int j = 0; j < 16; j++) { v[j] = __expf(v[j] - mx); s += v[j]; }
    s += __shfl_xor(s, 16);
    s += __shfl_xor(s, 32);
    float inv = 1.0f / s;
#pragma unroll
    for (int i = 0; i < 4; i++) {
      u16x4 o = (u16x4){f2bf(v[i * 4 + 0] * inv), f2bf(v[i * 4 + 1] * inv),
                        f2bf(v[i * 4 + 2] * inv), f2bf(v[i * 4 + 3] * inv)};
      *(u16x4*)(qbase + (4 * h + i) * 16 + quad * 4) = o;
    }
  }
}

// ---------------------------------------------------------------------------
// G2: KV = wkv @ cproj + bkv. 128x128 tiles. Rows <256 -> Kf fp32; >=256 -> Vb bf16.
__global__ __launch_bounds__(256) void kvproj(
    const float* __restrict__ wkv, const float* __restrict__ cp,
    const float* __restrict__ bkv, float* __restrict__ Kf,
    unsigned short* __restrict__ Vb) {
  __shared__ unsigned short As[128][40];   // [m][k]
  __shared__ unsigned short Bs[32][136];   // [k][n]
  const int b = blockIdx.z;
  const int m0 = blockIdx.y * 128, n0 = blockIdx.x * 128;
  const int tid = threadIdx.x, lane = tid & 63, w = tid >> 6;
  const int m0w = (w >> 1) * 64, n0w = (w & 1) * 64;
  const int colL = lane & 15, kq = lane >> 4;
  const float* cpb = cp + (size_t)b * C_ * N_;

  f32x4 acc[4][4];
#pragma unroll
  for (int i = 0; i < 4; i++)
#pragma unroll
    for (int j = 0; j < 4; j++) acc[i][j] = (f32x4){0.f, 0.f, 0.f, 0.f};

  for (int kc = 0; kc < C_; kc += 32) {
    __syncthreads();
#pragma unroll
    for (int i = 0; i < 4; i++) {  // A: wkv[m0+r][kc+c]
      int r = i * 32 + (tid >> 3), c = (tid & 7) * 4;
      float4 v = *(const float4*)&wkv[(size_t)(m0 + r) * C_ + kc + c];
      *(u16x4*)&As[r][c] = (u16x4){f2bf(v.x), f2bf(v.y), f2bf(v.z), f2bf(v.w)};
    }
#pragma unroll
    for (int i = 0; i < 4; i++) {  // B: cproj[kc+r][n0+c]
      int r = i * 8 + (tid >> 5), c = (tid & 31) * 4;
      float4 v = *(const float4*)&cpb[(size_t)(kc + r) * N_ + n0 + c];
      *(u16x4*)&Bs[r][c] = (u16x4){f2bf(v.x), f2bf(v.y), f2bf(v.z), f2bf(v.w)};
    }
    __syncthreads();

    bf16x8 bfr[4];
#pragma unroll
    for (int nt = 0; nt < 4; nt++) {
      BU8 bu;
#pragma unroll
      for (int j = 0; j < 8; j++) bu.u[j] = Bs[kq * 8 + j][n0w + nt * 16 + colL];
      bfr[nt] = bu.b;
    }
#pragma unroll
    for (int mt = 0; mt < 4; mt++) {
      bf16x8 af = *(const bf16x8*)&As[m0w + mt * 16 + colL][kq * 8];
#pragma unroll
      for (int nt = 0; nt < 4; nt++) acc[mt][nt] = mfma16(af, bfr[nt], acc[mt][nt]);
    }
  }

  const int quad = lane >> 4;
#pragma unroll
  for (int mt = 0; mt < 4; mt++) {
#pragma unroll
    for (int r = 0; r < 4; r++) {
      int m = m0 + m0w + mt * 16 + quad * 4 + r;
      float bias = bkv[m];
#pragma unroll
      for (int nt = 0; nt < 4; nt++) {
        int n = n0 + n0w + nt * 16 + colL;
        float val = acc[mt][nt][r] + bias;
        if (m0 < C_) {
          Kf[((size_t)b * C_ + m) * N_ + n] = val;
        } else {
          Vb[((size_t)b * C_ + (m - C_)) * N_ + n] = f2bf(val);
        }
      }
    }
  }
}

// ---------------------------------------------------------------------------
// G3: k = softmax_N(Kf) -> kb bf16, one block per (b, c) row of 4096.
__global__ __launch_bounds__(256) void ksoftmax(const float* __restrict__ Kf,
                                                unsigned short* __restrict__ kb) {
  const int b = blockIdx.x >> 8, c = blockIdx.x & 255;
  const float* row = Kf + ((size_t)b * C_ + c) * N_;
  unsigned short* orow = kb + ((size_t)b * C_ + c) * N_;
  const int t = threadIdx.x, lane = t & 63, wv = t >> 6;
  __shared__ float red[8];

  float4 v[4];
  float mx = -1e30f;
#pragma unroll
  for (int i = 0; i < 4; i++) {
    v[i] = *(const float4*)&row[i * 1024 + t * 4];
    mx = fmaxf(fmaxf(fmaxf(mx, v[i].x), fmaxf(v[i].y, v[i].z)), v[i].w);
  }
#pragma unroll
  for (int o = 32; o > 0; o >>= 1) mx = fmaxf(mx, __shfl_down(mx, o));
  if (lane == 0) red[wv] = mx;
  __syncthreads();
  mx = fmaxf(fmaxf(red[0], red[1]), fmaxf(red[2], red[3]));

  float s = 0.f;
#pragma unroll
  for (int i = 0; i < 4; i++) {
    v[i].x = __expf(v[i].x - mx); v[i].y = __expf(v[i].y - mx);
    v[i].z = __expf(v[i].z - mx); v[i].w = __expf(v[i].w - mx);
    s += v[i].x + v[i].y + v[i].z + v[i].w;
  }
#pragma unroll
  for (int o = 32; o > 0; o >>= 1) s += __shfl_down(s, o);
  if (lane == 0) red[4 + wv] = s;
  __syncthreads();
  float inv = 1.0f / (red[4] + red[5] + red[6] + red[7]);
#pragma unroll
  for (int i = 0; i < 4; i++) {
    u16x4 o = (u16x4){f2bf(v[i].x * inv), f2bf(v[i].y * inv),
                      f2bf(v[i].z * inv), f2bf(v[i].w * inv)};
    *(u16x4*)&orow[i * 1024 + t * 4] = o;
  }
}

// ---------------------------------------------------------------------------
// G4: ctxp[s][b][c][d] = sum_{n in split s} kb[b][c][n] * Vb[b][d][n]  (NT GEMM)
__global__ __launch_bounds__(256) void ctx_part(
    const unsigned short* __restrict__ kb, const unsigned short* __restrict__ Vb,
    float* __restrict__ ctxp) {
  __shared__ unsigned short As[128][40];
  __shared__ unsigned short Bs[128][40];
  const int z = blockIdx.z, b = z >> 3, s = z & 7;
  const int m0 = blockIdx.y * 128, n0 = blockIdx.x * 128;
  const int tid = threadIdx.x, lane = tid & 63, w = tid >> 6;
  const int m0w = (w >> 1) * 64, n0w = (w & 1) * 64;
  const int colL = lane & 15, kq = lane >> 4;
  const unsigned short* Ab = kb + (size_t)b * C_ * N_;
  const unsigned short* Bb = Vb + (size_t)b * C_ * N_;

  f32x4 acc[4][4];
#pragma unroll
  for (int i = 0; i < 4; i++)
#pragma unroll
    for (int j = 0; j < 4; j++) acc[i][j] = (f32x4){0.f, 0.f, 0.f, 0.f};

  const int kbeg = s * (N_ / NSPLIT);
  for (int kc = kbeg; kc < kbeg + N_ / NSPLIT; kc += 32) {
    __syncthreads();
#pragma unroll
    for (int i = 0; i < 2; i++) {
      int r = i * 64 + (tid >> 2), c = (tid & 3) * 8;
      *(u16x8*)&As[r][c] = *(const u16x8*)&Ab[(size_t)(m0 + r) * N_ + kc + c];
      *(u16x8*)&Bs[r][c] = *(const u16x8*)&Bb[(size_t)(n0 + r) * N_ + kc + c];
    }
    __syncthreads();

    bf16x8 af[4], bfr[4];
#pragma unroll
    for (int mt = 0; mt < 4; mt++) af[mt] = *(const bf16x8*)&As[m0w + mt * 16 + colL][kq * 8];
#pragma unroll
    for (int nt = 0; nt < 4; nt++) bfr[nt] = *(const bf16x8*)&Bs[n0w + nt * 16 + colL][kq * 8];
#pragma unroll
    for (int mt = 0; mt < 4; mt++)
#pragma unroll
      for (int nt = 0; nt < 4; nt++) acc[mt][nt] = mfma16(af[mt], bfr[nt], acc[mt][nt]);
  }

  float* outp = ctxp + ((size_t)s * B_ + b) * C_ * C_;
  const int quad = lane >> 4;
#pragma unroll
  for (int mt = 0; mt < 4; mt++)
#pragma unroll
    for (int nt = 0; nt < 4; nt++)
#pragma unroll
      for (int r = 0; r < 4; r++) {
        int m = m0 + m0w + mt * 16 + quad * 4 + r;
        int n = n0 + n0w + nt * 16 + colL;
        outp[(size_t)m * C_ + n] = acc[mt][nt][r];
      }
}

// ---------------------------------------------------------------------------
// R: ctxs bf16 = sum over 8 split partials
__global__ __launch_bounds__(256) void ctx_reduce(const float* __restrict__ ctxp,
                                                  unsigned short* __restrict__ ctxs) {
  const size_t e = ((size_t)blockIdx.x * 256 + threadIdx.x) * 4;
  float4 a = {0.f, 0.f, 0.f, 0.f};
#pragma unroll
  for (int s = 0; s < NSPLIT; s++) {
    float4 v = *(const float4*)&ctxp[(size_t)s * B_ * C_ * C_ + e];
    a.x += v.x; a.y += v.y; a.z += v.z; a.w += v.w;
  }
  *(u16x4*)&ctxs[e] = (u16x4){f2bf(a.x), f2bf(a.y), f2bf(a.z), f2bf(a.w)};
}

// ---------------------------------------------------------------------------
// G5: ctx2[b] = wo @ ctxs[b]  (256x256x256, bf16 out)
__global__ __launch_bounds__(256) void oproj(const float* __restrict__ wo,
                                             const unsigned short* __restrict__ ctxs,
                                             unsigned short* __restrict__ ctx2) {
  __shared__ unsigned short As[128][40];   // wo [m][k]
  __shared__ unsigned short Bs[32][136];   // ctxs [k][n]
  const int b = blockIdx.z;
  const int m0 = blockIdx.y * 128, n0 = blockIdx.x * 128;
  const int tid = threadIdx.x, lane = tid & 63, w = tid >> 6;
  const int m0w = (w >> 1) * 64, n0w = (w & 1) * 64;
  const int colL = lane & 15, kq = lane >> 4;
  const unsigned short* cb = ctxs + (size_t)b * C_ * C_;

  f32x4 acc[4][4];
#pragma unroll
  for (int i = 0; i < 4; i++)
#pragma unroll
    for (int j = 0; j < 4; j++) acc[i][j] = (f32x4){0.f, 0.f, 0.f, 0.f};

  for (int kc = 0; kc < C_; kc += 32) {
    __syncthreads();
#pragma unroll
    for (int i = 0; i < 4; i++) {
      int r = i * 32 + (tid >> 3), c = (tid & 7) * 4;
      float4 v = *(const float4*)&wo[(size_t)(m0 + r) * C_ + kc + c];
      *(u16x4*)&As[r][c] = (u16x4){f2bf(v.x), f2bf(v.y), f2bf(v.z), f2bf(v.w)};
    }
#pragma unroll
    for (int i = 0; i < 2; i++) {
      int r = i * 16 + (tid >> 4), c = (tid & 15) * 8;
      *(u16x8*)&Bs[r][c] = *(const u16x8*)&cb[(size_t)(kc + r) * C_ + n0 + c];
    }
    __syncthreads();

    bf16x8 bfr[4];
#pragma unroll
    for (int nt = 0; nt < 4; nt++) {
      BU8 bu;
#pragma unroll
      for (int j = 0; j < 8; j++) bu.u[j] = Bs[kq * 8 + j][n0w + nt * 16 + colL];
      bfr[nt] = bu.b;
    }
#pragma unroll
    for (int mt = 0; mt < 4; mt++) {
      bf16x8 af = *(const bf16x8*)&As[m0w + mt * 16 + colL][kq * 8];
#pragma unroll
      for (int nt = 0; nt < 4; nt++) acc[mt][nt] = mfma16(af, bfr[nt], acc[mt][nt]);
    }
  }

  unsigned short* ob = ctx2 + (size_t)b * C_ * C_;
  const int quad = lane >> 4;
#pragma unroll
  for (int mt = 0; mt < 4; mt++)
#pragma unroll
    for (int nt = 0; nt < 4; nt++)
#pragma unroll
      for (int r = 0; r < 4; r++) {
        int m = m0 + m0w + mt * 16 + quad * 4 + r;
        int n = n0 + n0w + nt * 16 + colL;
        ob[(size_t)m * C_ + n] = f2bf(acc[mt][nt][r]);
      }
}

// ---------------------------------------------------------------------------
// G6: out[b][m][n] = sum_d ctx2[b][m][d] * qT[b][n][d] + bo[m]  (NT GEMM, fp32 out)
__global__ __launch_bounds__(256) void outgemm(const unsigned short* __restrict__ ctx2,
                                               const unsigned short* __restrict__ qT,
                                               const float* __restrict__ bo,
                                               float* __restrict__ out) {
  __shared__ unsigned short As[128][40];
  __shared__ unsigned short Bs[128][40];
  const int b = blockIdx.z;
  const int n0 = blockIdx.x * 128, m0 = blockIdx.y * 128;
  const int tid = threadIdx.x, lane = tid & 63, w = tid >> 6;
  const int m0w = (w >> 1) * 64, n0w = (w & 1) * 64;
  const int colL = lane & 15, kq = lane >> 4;
  const unsigned short* Ab = ctx2 + (size_t)b * C_ * C_;
  const unsigned short* Bb = qT + (size_t)b * N_ * C_;

  f32x4 acc[4][4];
#pragma unroll
  for (int i = 0; i < 4; i++)
#pragma unroll
    for (int j = 0; j < 4; j++) acc[i][j] = (f32x4){0.f, 0.f, 0.f, 0.f};

  for (int kc = 0; kc < C_; kc += 32) {
    __syncthreads();
#pragma unroll
    for (int i = 0; i < 2; i++) {
      int r = i * 64 + (tid >> 2), c = (tid & 3) * 8;
      *(u16x8*)&As[r][c] = *(const u16x8*)&Ab[(size_t)(m0 + r) * C_ + kc + c];
      *(u16x8*)&Bs[r][c] = *(const u16x8*)&Bb[(size_t)(n0 + r) * C_ + kc + c];
    }
    __syncthreads();

    bf16x8 af[4], bfr[4];
#pragma unroll
    for (int mt = 0; mt < 4; mt++) af[mt] = *(const bf16x8*)&As[m0w + mt * 16 + colL][kq * 8];
#pragma unroll
    for (int nt = 0; nt < 4; nt++) bfr[nt] = *(const bf16x8*)&Bs[n0w + nt * 16 + colL][kq * 8];
#pragma unroll
    for (int mt = 0; mt < 4; mt++)
#pragma unroll
      for (int nt = 0; nt < 4; nt++) acc[mt][nt] = mfma16(af[mt], bfr[nt], acc[mt][nt]);
  }

  float* ob = out + (size_t)b * C_ * N_;
  const int quad = lane >> 4;
#pragma unroll
  for (int mt = 0; mt < 4; mt++)
#pragma unroll
    for (int r = 0; r < 4; r++) {
      int m = m0 + m0w + mt * 16 + quad * 4 + r;
      float bias = bo[m];
#pragma unroll
      for (int nt = 0; nt < 4; nt++) {
        int n = n0 + n0w + nt * 16 + colL;
        ob[(size_t)m * N_ + n] = acc[mt][nt][r] + bias;
      }
    }
}

// ---------------------------------------------------------------------------
extern "C" void kernel_launch(void* const* d_in, const int* in_sizes, int n_in,
                              void* d_out, int out_size, void* d_ws, size_t ws_size,
                              hipStream_t stream) {
  const float* x     = (const float*)d_in[0];
  const float* cproj = (const float*)d_in[1];
  const float* wq    = (const float*)d_in[2];
  const float* bq    = (const float*)d_in[3];
  const float* wkv   = (const float*)d_in[4];
  const float* bkv   = (const float*)d_in[5];
  const float* wo    = (const float*)d_in[6];
  const float* bo    = (const float*)d_in[7];
  float* out = (float*)d_out;

  // workspace layout (~103 MB)
  unsigned short* qT   = (unsigned short*)d_ws;                       // B*N*C bf16
  float*          Kf   = (float*)(qT + (size_t)B_ * N_ * C_);         // B*C*N fp32
  unsigned short* Vb   = (unsigned short*)(Kf + (size_t)B_ * C_ * N_);// B*C*N bf16
  unsigned short* kb   = Vb + (size_t)B_ * C_ * N_;                   // B*C*N bf16
  float*          ctxp = (float*)(kb + (size_t)B_ * C_ * N_);         // 8*B*C*C fp32
  unsigned short* ctxs = (unsigned short*)(ctxp + (size_t)NSPLIT * B_ * C_ * C_);
  unsigned short* ctx2 = ctxs + (size_t)B_ * C_ * C_;

  qproj_softmax<<<dim3(N_ / 64, 1, B_), 256, 0, stream>>>(wq, x, bq, qT);
  kvproj<<<dim3(N_ / 128, KVC_ / 128, B_), 256, 0, stream>>>(wkv, cproj, bkv, Kf, Vb);
  ksoftmax<<<dim3(B_ * C_), 256, 0, stream>>>(Kf, kb);
  ctx_part<<<dim3(2, 2, B_ * NSPLIT), 256, 0, stream>>>(kb, Vb, ctxp);
  ctx_reduce<<<dim3(B_ * C_ * C_ / 1024), 256, 0, stream>>>(ctxp, ctxs);
  oproj<<<dim3(2, 2, B_), 256, 0, stream>>>(wo, ctxs, ctx2);
  outgemm<<<dim3(N_ / 128, 2, B_), 256, 0, stream>>>(ctx2, qT, bo, out);
}

// Round 3
// 207.668 us; speedup vs baseline: 2.3485x; 1.0438x over previous
//
#include <hip/hip_runtime.h>

#define B_ 8
#define C_ 256
#define N_ 4096
#define H_ 4
#define KVC_ 512
#define NSPLIT 8

typedef float f32x4 __attribute__((ext_vector_type(4)));
typedef __bf16 bf16x8 __attribute__((ext_vector_type(8)));
typedef unsigned short u16x8 __attribute__((ext_vector_type(8)));
typedef unsigned short u16x4 __attribute__((ext_vector_type(4)));

union BU8 { u16x8 u; bf16x8 b; };

__device__ __forceinline__ unsigned short f2bf(float f) {
  unsigned u = __float_as_uint(f);
  u += 0x7fff + ((u >> 16) & 1);   // RNE; inputs are finite/no-NaN
  return (unsigned short)(u >> 16);
}

__device__ __forceinline__ f32x4 mfma16(bf16x8 a, bf16x8 b, f32x4 c) {
  return __builtin_amdgcn_mfma_f32_16x16x32_bf16(a, b, c, 0, 0, 0);
}

// ---------------------------------------------------------------------------
// G1: qT[b][n][m] = softmax_d((wq @ x + bq) * 0.25), written bf16 transposed.
// M-tile = 256 (full C) x N-tile 64. Register-prefetch pipelined K-loop (BK=32).
__global__ __launch_bounds__(256) void qproj_softmax(
    const float* __restrict__ wq, const float* __restrict__ x,
    const float* __restrict__ bq, unsigned short* __restrict__ qT) {
  __shared__ unsigned short As[256][40];  // [m][k]
  __shared__ unsigned short Bs[32][68];   // [k][n]
  __shared__ float bql[C_];
  const int b = blockIdx.z;
  const int n0 = blockIdx.x * 64;
  const int tid = threadIdx.x;
  const int lane = tid & 63, w = tid >> 6;
  const float* xb = x + (size_t)b * C_ * N_;

  bql[tid] = bq[tid];

  f32x4 acc[16];
#pragma unroll
  for (int i = 0; i < 16; i++) acc[i] = (f32x4){0.f, 0.f, 0.f, 0.f};

  const int colL = lane & 15, kq = lane >> 4;
  const int ra = tid >> 3, ca = (tid & 7) * 4;
  const int rb = tid >> 4, cb = (tid & 15) * 4;

  float4 pa[8], pb[2];
  // prologue: prefetch tile 0
#pragma unroll
  for (int i = 0; i < 8; i++) pa[i] = *(const float4*)&wq[(i * 32 + ra) * C_ + ca];
#pragma unroll
  for (int i = 0; i < 2; i++) pb[i] = *(const float4*)&xb[(size_t)(i * 16 + rb) * N_ + n0 + cb];

  for (int kt = 0; kt < 8; kt++) {
    // store prefetched tile to LDS (converted)
#pragma unroll
    for (int i = 0; i < 8; i++) {
      float4 v = pa[i];
      *(u16x4*)&As[i * 32 + ra][ca] = (u16x4){f2bf(v.x), f2bf(v.y), f2bf(v.z), f2bf(v.w)};
    }
#pragma unroll
    for (int i = 0; i < 2; i++) {
      float4 v = pb[i];
      *(u16x4*)&Bs[i * 16 + rb][cb] = (u16x4){f2bf(v.x), f2bf(v.y), f2bf(v.z), f2bf(v.w)};
    }
    __syncthreads();
    if (kt < 7) {
      const int kc = (kt + 1) * 32;
#pragma unroll
      for (int i = 0; i < 8; i++) pa[i] = *(const float4*)&wq[(i * 32 + ra) * C_ + kc + ca];
#pragma unroll
      for (int i = 0; i < 2; i++) pb[i] = *(const float4*)&xb[(size_t)(kc + i * 16 + rb) * N_ + n0 + cb];
    }
    BU8 bu;
#pragma unroll
    for (int j = 0; j < 8; j++) bu.u[j] = Bs[kq * 8 + j][w * 16 + colL];
    bf16x8 bf = bu.b;
#pragma unroll
    for (int mt = 0; mt < 16; mt++) {
      bf16x8 af = *(const bf16x8*)&As[mt * 16 + colL][kq * 8];
      acc[mt] = mfma16(af, bf, acc[mt]);
    }
    __syncthreads();
  }

  // epilogue: bias+scale, per-head softmax over 64 rows, write qT bf16
  const int quad = lane >> 4;
  const int n = n0 + w * 16 + colL;
  unsigned short* qbase = qT + ((size_t)b * N_ + n) * C_;
#pragma unroll
  for (int h = 0; h < H_; h++) {
    float v[16];
    float mx = -1e30f;
#pragma unroll
    for (int i = 0; i < 4; i++) {
      int mt = 4 * h + i;
#pragma unroll
      for (int r = 0; r < 4; r++) {
        int m = mt * 16 + quad * 4 + r;
        float val = (acc[mt][r] + bql[m]) * 0.25f;
        v[i * 4 + r] = val;
        mx = fmaxf(mx, val);
      }
    }
    mx = fmaxf(mx, __shfl_xor(mx, 16));
    mx = fmaxf(mx, __shfl_xor(mx, 32));
    float s = 0.f;
#pragma unroll
    for (int j = 0; j < 16; j++) { v[j] = __expf(v[j] - mx); s += v[j]; }
    s += __shfl_xor(s, 16);
    s += __shfl_xor(s, 32);
    float inv = 1.0f / s;
#pragma unroll
    for (int i = 0; i < 4; i++) {
      u16x4 o = (u16x4){f2bf(v[i * 4 + 0] * inv), f2bf(v[i * 4 + 1] * inv),
                        f2bf(v[i * 4 + 2] * inv), f2bf(v[i * 4 + 3] * inv)};
      *(u16x4*)(qbase + (4 * h + i) * 16 + quad * 4) = o;
    }
  }
}

// ---------------------------------------------------------------------------
// G2: KV = wkv @ cproj + bkv. 128x128 tiles, BK=32, register-prefetch pipeline.
__global__ __launch_bounds__(256) void kvproj(
    const float* __restrict__ wkv, const float* __restrict__ cp,
    const float* __restrict__ bkv, float* __restrict__ Kf,
    unsigned short* __restrict__ Vb) {
  __shared__ unsigned short As[128][40];   // [m][k]
  __shared__ unsigned short Bs[32][136];   // [k][n]
  const int b = blockIdx.z;
  const int m0 = blockIdx.y * 128, n0 = blockIdx.x * 128;
  const int tid = threadIdx.x, lane = tid & 63, w = tid >> 6;
  const int m0w = (w >> 1) * 64, n0w = (w & 1) * 64;
  const int colL = lane & 15, kq = lane >> 4;
  const float* cpb = cp + (size_t)b * C_ * N_;

  f32x4 acc[4][4];
#pragma unroll
  for (int i = 0; i < 4; i++)
#pragma unroll
    for (int j = 0; j < 4; j++) acc[i][j] = (f32x4){0.f, 0.f, 0.f, 0.f};

  const int ra = tid >> 3, ca = (tid & 7) * 4;
  const int rb = tid >> 5, cb = (tid & 31) * 4;

  float4 pa[4], pb[4];
#pragma unroll
  for (int i = 0; i < 4; i++) pa[i] = *(const float4*)&wkv[(size_t)(m0 + i * 32 + ra) * C_ + ca];
#pragma unroll
  for (int i = 0; i < 4; i++) pb[i] = *(const float4*)&cpb[(size_t)(i * 8 + rb) * N_ + n0 + cb];

  for (int kt = 0; kt < 8; kt++) {
#pragma unroll
    for (int i = 0; i < 4; i++) {
      float4 v = pa[i];
      *(u16x4*)&As[i * 32 + ra][ca] = (u16x4){f2bf(v.x), f2bf(v.y), f2bf(v.z), f2bf(v.w)};
    }
#pragma unroll
    for (int i = 0; i < 4; i++) {
      float4 v = pb[i];
      *(u16x4*)&Bs[i * 8 + rb][cb] = (u16x4){f2bf(v.x), f2bf(v.y), f2bf(v.z), f2bf(v.w)};
    }
    __syncthreads();
    if (kt < 7) {
      const int kc = (kt + 1) * 32;
#pragma unroll
      for (int i = 0; i < 4; i++) pa[i] = *(const float4*)&wkv[(size_t)(m0 + i * 32 + ra) * C_ + kc + ca];
#pragma unroll
      for (int i = 0; i < 4; i++) pb[i] = *(const float4*)&cpb[(size_t)(kc + i * 8 + rb) * N_ + n0 + cb];
    }
    bf16x8 bfr[4];
#pragma unroll
    for (int nt = 0; nt < 4; nt++) {
      BU8 bu;
#pragma unroll
      for (int j = 0; j < 8; j++) bu.u[j] = Bs[kq * 8 + j][n0w + nt * 16 + colL];
      bfr[nt] = bu.b;
    }
#pragma unroll
    for (int mt = 0; mt < 4; mt++) {
      bf16x8 af = *(const bf16x8*)&As[m0w + mt * 16 + colL][kq * 8];
#pragma unroll
      for (int nt = 0; nt < 4; nt++) acc[mt][nt] = mfma16(af, bfr[nt], acc[mt][nt]);
    }
    __syncthreads();
  }

  const int quad = lane >> 4;
#pragma unroll
  for (int mt = 0; mt < 4; mt++) {
#pragma unroll
    for (int r = 0; r < 4; r++) {
      int m = m0 + m0w + mt * 16 + quad * 4 + r;
      float bias = bkv[m];
#pragma unroll
      for (int nt = 0; nt < 4; nt++) {
        int n = n0 + n0w + nt * 16 + colL;
        float val = acc[mt][nt][r] + bias;
        if (m0 < C_) {
          Kf[((size_t)b * C_ + m) * N_ + n] = val;
        } else {
          Vb[((size_t)b * C_ + (m - C_)) * N_ + n] = f2bf(val);
        }
      }
    }
  }
}

// ---------------------------------------------------------------------------
// G3: k = softmax_N(Kf) -> kb bf16, one block per (b, c) row of 4096.
__global__ __launch_bounds__(256) void ksoftmax(const float* __restrict__ Kf,
                                                unsigned short* __restrict__ kb) {
  const int b = blockIdx.x >> 8, c = blockIdx.x & 255;
  const float* row = Kf + ((size_t)b * C_ + c) * N_;
  unsigned short* orow = kb + ((size_t)b * C_ + c) * N_;
  const int t = threadIdx.x, lane = t & 63, wv = t >> 6;
  __shared__ float red[8];

  float4 v[4];
  float mx = -1e30f;
#pragma unroll
  for (int i = 0; i < 4; i++) {
    v[i] = *(const float4*)&row[i * 1024 + t * 4];
    mx = fmaxf(fmaxf(fmaxf(mx, v[i].x), fmaxf(v[i].y, v[i].z)), v[i].w);
  }
#pragma unroll
  for (int o = 32; o > 0; o >>= 1) mx = fmaxf(mx, __shfl_down(mx, o));
  if (lane == 0) red[wv] = mx;
  __syncthreads();
  mx = fmaxf(fmaxf(red[0], red[1]), fmaxf(red[2], red[3]));

  float s = 0.f;
#pragma unroll
  for (int i = 0; i < 4; i++) {
    v[i].x = __expf(v[i].x - mx); v[i].y = __expf(v[i].y - mx);
    v[i].z = __expf(v[i].z - mx); v[i].w = __expf(v[i].w - mx);
    s += v[i].x + v[i].y + v[i].z + v[i].w;
  }
#pragma unroll
  for (int o = 32; o > 0; o >>= 1) s += __shfl_down(s, o);
  if (lane == 0) red[4 + wv] = s;
  __syncthreads();
  float inv = 1.0f / (red[4] + red[5] + red[6] + red[7]);
#pragma unroll
  for (int i = 0; i < 4; i++) {
    u16x4 o = (u16x4){f2bf(v[i].x * inv), f2bf(v[i].y * inv),
                      f2bf(v[i].z * inv), f2bf(v[i].w * inv)};
    *(u16x4*)&orow[i * 1024 + t * 4] = o;
  }
}

// ---------------------------------------------------------------------------
// G4: ctxp[s][b][c][d] = sum_{n in split s} kb[b][c][n] * Vb[b][d][n]  (NT GEMM)
// BK=64, register-prefetch pipeline.
__global__ __launch_bounds__(256) void ctx_part(
    const unsigned short* __restrict__ kb, const unsigned short* __restrict__ Vb,
    float* __restrict__ ctxp) {
  __shared__ unsigned short As[128][72];
  __shared__ unsigned short Bs[128][72];
  const int z = blockIdx.z, b = z >> 3, s = z & 7;
  const int m0 = blockIdx.y * 128, n0 = blockIdx.x * 128;
  const int tid = threadIdx.x, lane = tid & 63, w = tid >> 6;
  const int m0w = (w >> 1) * 64, n0w = (w & 1) * 64;
  const int colL = lane & 15, kq = lane >> 4;
  const unsigned short* Ab = kb + (size_t)b * C_ * N_;
  const unsigned short* Bb = Vb + (size_t)b * C_ * N_;

  f32x4 acc[4][4];
#pragma unroll
  for (int i = 0; i < 4; i++)
#pragma unroll
    for (int j = 0; j < 4; j++) acc[i][j] = (f32x4){0.f, 0.f, 0.f, 0.f};

  const int rs = tid >> 3, cs = (tid & 7) * 8;
  const int kbeg = s * (N_ / NSPLIT);

  u16x8 pa[4], pb[4];
#pragma unroll
  for (int i = 0; i < 4; i++) {
    pa[i] = *(const u16x8*)&Ab[(size_t)(m0 + i * 32 + rs) * N_ + kbeg + cs];
    pb[i] = *(const u16x8*)&Bb[(size_t)(n0 + i * 32 + rs) * N_ + kbeg + cs];
  }

  for (int kt = 0; kt < (N_ / NSPLIT) / 64; kt++) {
#pragma unroll
    for (int i = 0; i < 4; i++) {
      *(u16x8*)&As[i * 32 + rs][cs] = pa[i];
      *(u16x8*)&Bs[i * 32 + rs][cs] = pb[i];
    }
    __syncthreads();
    if (kt < (N_ / NSPLIT) / 64 - 1) {
      const int kc = kbeg + (kt + 1) * 64;
#pragma unroll
      for (int i = 0; i < 4; i++) {
        pa[i] = *(const u16x8*)&Ab[(size_t)(m0 + i * 32 + rs) * N_ + kc + cs];
        pb[i] = *(const u16x8*)&Bb[(size_t)(n0 + i * 32 + rs) * N_ + kc + cs];
      }
    }
#pragma unroll
    for (int ks = 0; ks < 2; ks++) {
      bf16x8 af[4], bfr[4];
#pragma unroll
      for (int mt = 0; mt < 4; mt++) af[mt] = *(const bf16x8*)&As[m0w + mt * 16 + colL][ks * 32 + kq * 8];
#pragma unroll
      for (int nt = 0; nt < 4; nt++) bfr[nt] = *(const bf16x8*)&Bs[n0w + nt * 16 + colL][ks * 32 + kq * 8];
#pragma unroll
      for (int mt = 0; mt < 4; mt++)
#pragma unroll
        for (int nt = 0; nt < 4; nt++) acc[mt][nt] = mfma16(af[mt], bfr[nt], acc[mt][nt]);
    }
    __syncthreads();
  }

  float* outp = ctxp + ((size_t)s * B_ + b) * C_ * C_;
  const int quad = lane >> 4;
#pragma unroll
  for (int mt = 0; mt < 4; mt++)
#pragma unroll
    for (int nt = 0; nt < 4; nt++)
#pragma unroll
      for (int r = 0; r < 4; r++) {
        int m = m0 + m0w + mt * 16 + quad * 4 + r;
        int n = n0 + n0w + nt * 16 + colL;
        outp[(size_t)m * C_ + n] = acc[mt][nt][r];
      }
}

// ---------------------------------------------------------------------------
// R: ctxs bf16 = sum over 8 split partials
__global__ __launch_bounds__(256) void ctx_reduce(const float* __restrict__ ctxp,
                                                  unsigned short* __restrict__ ctxs) {
  const size_t e = ((size_t)blockIdx.x * 256 + threadIdx.x) * 4;
  float4 a = {0.f, 0.f, 0.f, 0.f};
#pragma unroll
  for (int s = 0; s < NSPLIT; s++) {
    float4 v = *(const float4*)&ctxp[(size_t)s * B_ * C_ * C_ + e];
    a.x += v.x; a.y += v.y; a.z += v.z; a.w += v.w;
  }
  *(u16x4*)&ctxs[e] = (u16x4){f2bf(a.x), f2bf(a.y), f2bf(a.z), f2bf(a.w)};
}

// ---------------------------------------------------------------------------
// G5: ctx2[b] = wo @ ctxs[b]  (256x256x256, bf16 out)
__global__ __launch_bounds__(256) void oproj(const float* __restrict__ wo,
                                             const unsigned short* __restrict__ ctxs,
                                             unsigned short* __restrict__ ctx2) {
  __shared__ unsigned short As[128][40];   // wo [m][k]
  __shared__ unsigned short Bs[32][136];   // ctxs [k][n]
  const int b = blockIdx.z;
  const int m0 = blockIdx.y * 128, n0 = blockIdx.x * 128;
  const int tid = threadIdx.x, lane = tid & 63, w = tid >> 6;
  const int m0w = (w >> 1) * 64, n0w = (w & 1) * 64;
  const int colL = lane & 15, kq = lane >> 4;
  const unsigned short* cb = ctxs + (size_t)b * C_ * C_;

  f32x4 acc[4][4];
#pragma unroll
  for (int i = 0; i < 4; i++)
#pragma unroll
    for (int j = 0; j < 4; j++) acc[i][j] = (f32x4){0.f, 0.f, 0.f, 0.f};

  for (int kc = 0; kc < C_; kc += 32) {
    __syncthreads();
#pragma unroll
    for (int i = 0; i < 4; i++) {
      int r = i * 32 + (tid >> 3), c = (tid & 7) * 4;
      float4 v = *(const float4*)&wo[(size_t)(m0 + r) * C_ + kc + c];
      *(u16x4*)&As[r][c] = (u16x4){f2bf(v.x), f2bf(v.y), f2bf(v.z), f2bf(v.w)};
    }
#pragma unroll
    for (int i = 0; i < 2; i++) {
      int r = i * 16 + (tid >> 4), c = (tid & 15) * 8;
      *(u16x8*)&Bs[r][c] = *(const u16x8*)&cb[(size_t)(kc + r) * C_ + n0 + c];
    }
    __syncthreads();

    bf16x8 bfr[4];
#pragma unroll
    for (int nt = 0; nt < 4; nt++) {
      BU8 bu;
#pragma unroll
      for (int j = 0; j < 8; j++) bu.u[j] = Bs[kq * 8 + j][n0w + nt * 16 + colL];
      bfr[nt] = bu.b;
    }
#pragma unroll
    for (int mt = 0; mt < 4; mt++) {
      bf16x8 af = *(const bf16x8*)&As[m0w + mt * 16 + colL][kq * 8];
#pragma unroll
      for (int nt = 0; nt < 4; nt++) acc[mt][nt] = mfma16(af, bfr[nt], acc[mt][nt]);
    }
  }

  unsigned short* ob = ctx2 + (size_t)b * C_ * C_;
  const int quad = lane >> 4;
#pragma unroll
  for (int mt = 0; mt < 4; mt++)
#pragma unroll
    for (int nt = 0; nt < 4; nt++)
#pragma unroll
      for (int r = 0; r < 4; r++) {
        int m = m0 + m0w + mt * 16 + quad * 4 + r;
        int n = n0 + n0w + nt * 16 + colL;
        ob[(size_t)m * C_ + n] = f2bf(acc[mt][nt][r]);
      }
}

// ---------------------------------------------------------------------------
// G6: out[b][m][n] = sum_d ctx2[b][m][d] * qT[b][n][d] + bo[m]  (NT GEMM, fp32 out)
// BK=64, register-prefetch pipeline.
__global__ __launch_bounds__(256) void outgemm(const unsigned short* __restrict__ ctx2,
                                               const unsigned short* __restrict__ qT,
                                               const float* __restrict__ bo,
                                               float* __restrict__ out) {
  __shared__ unsigned short As[128][72];
  __shared__ unsigned short Bs[128][72];
  const int b = blockIdx.z;
  const int n0 = blockIdx.x * 128, m0 = blockIdx.y * 128;
  const int tid = threadIdx.x, lane = tid & 63, w = tid >> 6;
  const int m0w = (w >> 1) * 64, n0w = (w & 1) * 64;
  const int colL = lane & 15, kq = lane >> 4;
  const unsigned short* Ab = ctx2 + (size_t)b * C_ * C_;
  const unsigned short* Bb = qT + (size_t)b * N_ * C_;

  f32x4 acc[4][4];
#pragma unroll
  for (int i = 0; i < 4; i++)
#pragma unroll
    for (int j = 0; j < 4; j++) acc[i][j] = (f32x4){0.f, 0.f, 0.f, 0.f};

  const int rs = tid >> 3, cs = (tid & 7) * 8;

  u16x8 pa[4], pb[4];
#pragma unroll
  for (int i = 0; i < 4; i++) {
    pa[i] = *(const u16x8*)&Ab[(size_t)(m0 + i * 32 + rs) * C_ + cs];
    pb[i] = *(const u16x8*)&Bb[(size_t)(n0 + i * 32 + rs) * C_ + cs];
  }

  for (int kt = 0; kt < 4; kt++) {
#pragma unroll
    for (int i = 0; i < 4; i++) {
      *(u16x8*)&As[i * 32 + rs][cs] = pa[i];
      *(u16x8*)&Bs[i * 32 + rs][cs] = pb[i];
    }
    __syncthreads();
    if (kt < 3) {
      const int kc = (kt + 1) * 64;
#pragma unroll
      for (int i = 0; i < 4; i++) {
        pa[i] = *(const u16x8*)&Ab[(size_t)(m0 + i * 32 + rs) * C_ + kc + cs];
        pb[i] = *(const u16x8*)&Bb[(size_t)(n0 + i * 32 + rs) * C_ + kc + cs];
      }
    }
#pragma unroll
    for (int ks = 0; ks < 2; ks++) {
      bf16x8 af[4], bfr[4];
#pragma unroll
      for (int mt = 0; mt < 4; mt++) af[mt] = *(const bf16x8*)&As[m0w + mt * 16 + colL][ks * 32 + kq * 8];
#pragma unroll
      for (int nt = 0; nt < 4; nt++) bfr[nt] = *(const bf16x8*)&Bs[n0w + nt * 16 + colL][ks * 32 + kq * 8];
#pragma unroll
      for (int mt = 0; mt < 4; mt++)
#pragma unroll
        for (int nt = 0; nt < 4; nt++) acc[mt][nt] = mfma16(af[mt], bfr[nt], acc[mt][nt]);
    }
    __syncthreads();
  }

  float* ob = out + (size_t)b * C_ * N_;
  const int quad = lane >> 4;
#pragma unroll
  for (int mt = 0; mt < 4; mt++)
#pragma unroll
    for (int r = 0; r < 4; r++) {
      int m = m0 + m0w + mt * 16 + quad * 4 + r;
      float bias = bo[m];
#pragma unroll
      for (int nt = 0; nt < 4; nt++) {
        int n = n0 + n0w + nt * 16 + colL;
        ob[(size_t)m * N_ + n] = acc[mt][nt][r] + bias;
      }
    }
}

// ---------------------------------------------------------------------------
extern "C" void kernel_launch(void* const* d_in, const int* in_sizes, int n_in,
                              void* d_out, int out_size, void* d_ws, size_t ws_size,
                              hipStream_t stream) {
  const float* x     = (const float*)d_in[0];
  const float* cproj = (const float*)d_in[1];
  const float* wq    = (const float*)d_in[2];
  const float* bq    = (const float*)d_in[3];
  const float* wkv   = (const float*)d_in[4];
  const float* bkv   = (const float*)d_in[5];
  const float* wo    = (const float*)d_in[6];
  const float* bo    = (const float*)d_in[7];
  float* out = (float*)d_out;

  // workspace layout (~103 MB)
  unsigned short* qT   = (unsigned short*)d_ws;                       // B*N*C bf16
  float*          Kf   = (float*)(qT + (size_t)B_ * N_ * C_);         // B*C*N fp32
  unsigned short* Vb   = (unsigned short*)(Kf + (size_t)B_ * C_ * N_);// B*C*N bf16
  unsigned short* kb   = Vb + (size_t)B_ * C_ * N_;                   // B*C*N bf16
  float*          ctxp = (float*)(kb + (size_t)B_ * C_ * N_);         // 8*B*C*C fp32
  unsigned short* ctxs = (unsigned short*)(ctxp + (size_t)NSPLIT * B_ * C_ * C_);
  unsigned short* ctx2 = ctxs + (size_t)B_ * C_ * C_;

  qproj_softmax<<<dim3(N_ / 64, 1, B_), 256, 0, stream>>>(wq, x, bq, qT);
  kvproj<<<dim3(N_ / 128, KVC_ / 128, B_), 256, 0, stream>>>(wkv, cproj, bkv, Kf, Vb);
  ksoftmax<<<dim3(B_ * C_), 256, 0, stream>>>(Kf, kb);
  ctx_part<<<dim3(2, 2, B_ * NSPLIT), 256, 0, stream>>>(kb, Vb, ctxp);
  ctx_reduce<<<dim3(B_ * C_ * C_ / 1024), 256, 0, stream>>>(ctxp, ctxs);
  oproj<<<dim3(2, 2, B_), 256, 0, stream>>>(wo, ctxs, ctx2);
  outgemm<<<dim3(N_ / 128, 2, B_), 256, 0, stream>>>(ctx2, qT, bo, out);
}

// Round 4
// 204.728 us; speedup vs baseline: 2.3822x; 1.0144x over previous
//
#include <hip/hip_runtime.h>

#define B_ 8
#define C_ 256
#define N_ 4096
#define H_ 4
#define KVC_ 512
#define NSPLIT 8

typedef float f32x4 __attribute__((ext_vector_type(4)));
typedef __bf16 bf16x8 __attribute__((ext_vector_type(8)));
typedef unsigned short u16x8 __attribute__((ext_vector_type(8)));
typedef unsigned short u16x4 __attribute__((ext_vector_type(4)));

__device__ __forceinline__ unsigned short f2bf(float f) {
  unsigned u = __float_as_uint(f);
  u += 0x7fff + ((u >> 16) & 1);   // RNE; inputs are finite/no-NaN
  return (unsigned short)(u >> 16);
}
__device__ __forceinline__ unsigned pack2(float lo, float hi) {
  return (unsigned)f2bf(lo) | ((unsigned)f2bf(hi) << 16);
}

__device__ __forceinline__ f32x4 mfma16(bf16x8 a, bf16x8 b, f32x4 c) {
  return __builtin_amdgcn_mfma_f32_16x16x32_bf16(a, b, c, 0, 0, 0);
}

// ---------------------------------------------------------------------------
// G1: qT[b][n][m] = softmax_d((wq @ x + bq) * 0.25), bf16, transposed out.
// M-tile 256 x N-tile 64, BK=32. B staged TRANSPOSED [n][k] -> b128 frag reads.
__global__ __launch_bounds__(256) void qproj_softmax(
    const float* __restrict__ wq, const float* __restrict__ x,
    const float* __restrict__ bq, unsigned short* __restrict__ qT) {
  __shared__ unsigned short As[256][40];  // [m][k]
  __shared__ unsigned short Bs[64][40];   // [n][k]  (transposed)
  __shared__ float bql[C_];
  const int b = blockIdx.z;
  const int n0 = blockIdx.x * 64;
  const int tid = threadIdx.x;
  const int lane = tid & 63, w = tid >> 6;
  const float* xb = x + (size_t)b * C_ * N_;

  bql[tid] = bq[tid];

  f32x4 acc[16];
#pragma unroll
  for (int i = 0; i < 16; i++) acc[i] = (f32x4){0.f, 0.f, 0.f, 0.f};

  const int colL = lane & 15, kq = lane >> 4;
  const int ra = tid >> 3, ca = (tid & 7) * 4;       // A staging
  const int kp = tid >> 4, nf = tid & 15;            // B staging: k=2kp, n=4nf

  float4 pa[8], pb0, pb1;
#pragma unroll
  for (int i = 0; i < 8; i++) pa[i] = *(const float4*)&wq[(i * 32 + ra) * C_ + ca];
  pb0 = *(const float4*)&xb[(size_t)(2 * kp) * N_ + n0 + 4 * nf];
  pb1 = *(const float4*)&xb[(size_t)(2 * kp + 1) * N_ + n0 + 4 * nf];

  for (int kt = 0; kt < 8; kt++) {
#pragma unroll
    for (int i = 0; i < 8; i++) {
      float4 v = pa[i];
      *(u16x4*)&As[i * 32 + ra][ca] = (u16x4){f2bf(v.x), f2bf(v.y), f2bf(v.z), f2bf(v.w)};
    }
    {
      const float* q0 = (const float*)&pb0;
      const float* q1 = (const float*)&pb1;
#pragma unroll
      for (int j = 0; j < 4; j++)
        *(unsigned*)&Bs[4 * nf + j][2 * kp] = pack2(q0[j], q1[j]);
    }
    __syncthreads();
    if (kt < 7) {
      const int kc = (kt + 1) * 32;
#pragma unroll
      for (int i = 0; i < 8; i++) pa[i] = *(const float4*)&wq[(i * 32 + ra) * C_ + kc + ca];
      pb0 = *(const float4*)&xb[(size_t)(kc + 2 * kp) * N_ + n0 + 4 * nf];
      pb1 = *(const float4*)&xb[(size_t)(kc + 2 * kp + 1) * N_ + n0 + 4 * nf];
    }
    bf16x8 bf = *(const bf16x8*)&Bs[w * 16 + colL][kq * 8];
#pragma unroll
    for (int mt = 0; mt < 16; mt++) {
      bf16x8 af = *(const bf16x8*)&As[mt * 16 + colL][kq * 8];
      acc[mt] = mfma16(af, bf, acc[mt]);
    }
    __syncthreads();
  }

  // epilogue: bias+scale, per-head softmax over 64 rows, write qT bf16
  const int quad = lane >> 4;
  const int n = n0 + w * 16 + colL;
  unsigned short* qbase = qT + ((size_t)b * N_ + n) * C_;
#pragma unroll
  for (int h = 0; h < H_; h++) {
    float v[16];
    float mx = -1e30f;
#pragma unroll
    for (int i = 0; i < 4; i++) {
      int mt = 4 * h + i;
#pragma unroll
      for (int r = 0; r < 4; r++) {
        int m = mt * 16 + quad * 4 + r;
        float val = (acc[mt][r] + bql[m]) * 0.25f;
        v[i * 4 + r] = val;
        mx = fmaxf(mx, val);
      }
    }
    mx = fmaxf(mx, __shfl_xor(mx, 16));
    mx = fmaxf(mx, __shfl_xor(mx, 32));
    float s = 0.f;
#pragma unroll
    for (int j = 0; j < 16; j++) { v[j] = __expf(v[j] - mx); s += v[j]; }
    s += __shfl_xor(s, 16);
    s += __shfl_xor(s, 32);
    float inv = 1.0f / s;
#pragma unroll
    for (int i = 0; i < 4; i++) {
      u16x4 o = (u16x4){f2bf(v[i * 4 + 0] * inv), f2bf(v[i * 4 + 1] * inv),
                        f2bf(v[i * 4 + 2] * inv), f2bf(v[i * 4 + 3] * inv)};
      *(u16x4*)(qbase + (4 * h + i) * 16 + quad * 4) = o;
    }
  }
}

// ---------------------------------------------------------------------------
// G2: KV = wkv @ cproj + bkv. 128x128 tiles, BK=32, transposed B staging.
__global__ __launch_bounds__(256) void kvproj(
    const float* __restrict__ wkv, const float* __restrict__ cp,
    const float* __restrict__ bkv, float* __restrict__ Kf,
    unsigned short* __restrict__ Vb) {
  __shared__ unsigned short As[128][40];   // [m][k]
  __shared__ unsigned short Bs[128][40];   // [n][k]  (transposed)
  const int b = blockIdx.z;
  const int m0 = blockIdx.y * 128, n0 = blockIdx.x * 128;
  const int tid = threadIdx.x, lane = tid & 63, w = tid >> 6;
  const int m0w = (w >> 1) * 64, n0w = (w & 1) * 64;
  const int colL = lane & 15, kq = lane >> 4;
  const float* cpb = cp + (size_t)b * C_ * N_;

  f32x4 acc[4][4];
#pragma unroll
  for (int i = 0; i < 4; i++)
#pragma unroll
    for (int j = 0; j < 4; j++) acc[i][j] = (f32x4){0.f, 0.f, 0.f, 0.f};

  const int ra = tid >> 3, ca = (tid & 7) * 4;
  const int kp = tid >> 4, nf2 = tid & 15;   // k=2kp; n = 4*(nf2+16i)

  float4 pa[4], pb[2][2];
#pragma unroll
  for (int i = 0; i < 4; i++) pa[i] = *(const float4*)&wkv[(size_t)(m0 + i * 32 + ra) * C_ + ca];
#pragma unroll
  for (int i = 0; i < 2; i++) {
    pb[i][0] = *(const float4*)&cpb[(size_t)(2 * kp) * N_ + n0 + 4 * nf2 + 64 * i];
    pb[i][1] = *(const float4*)&cpb[(size_t)(2 * kp + 1) * N_ + n0 + 4 * nf2 + 64 * i];
  }

  for (int kt = 0; kt < 8; kt++) {
#pragma unroll
    for (int i = 0; i < 4; i++) {
      float4 v = pa[i];
      *(u16x4*)&As[i * 32 + ra][ca] = (u16x4){f2bf(v.x), f2bf(v.y), f2bf(v.z), f2bf(v.w)};
    }
#pragma unroll
    for (int i = 0; i < 2; i++) {
      const float* q0 = (const float*)&pb[i][0];
      const float* q1 = (const float*)&pb[i][1];
#pragma unroll
      for (int j = 0; j < 4; j++)
        *(unsigned*)&Bs[4 * nf2 + 64 * i + j][2 * kp] = pack2(q0[j], q1[j]);
    }
    __syncthreads();
    if (kt < 7) {
      const int kc = (kt + 1) * 32;
#pragma unroll
      for (int i = 0; i < 4; i++) pa[i] = *(const float4*)&wkv[(size_t)(m0 + i * 32 + ra) * C_ + kc + ca];
#pragma unroll
      for (int i = 0; i < 2; i++) {
        pb[i][0] = *(const float4*)&cpb[(size_t)(kc + 2 * kp) * N_ + n0 + 4 * nf2 + 64 * i];
        pb[i][1] = *(const float4*)&cpb[(size_t)(kc + 2 * kp + 1) * N_ + n0 + 4 * nf2 + 64 * i];
      }
    }
    bf16x8 bfr[4];
#pragma unroll
    for (int nt = 0; nt < 4; nt++) bfr[nt] = *(const bf16x8*)&Bs[n0w + nt * 16 + colL][kq * 8];
#pragma unroll
    for (int mt = 0; mt < 4; mt++) {
      bf16x8 af = *(const bf16x8*)&As[m0w + mt * 16 + colL][kq * 8];
#pragma unroll
      for (int nt = 0; nt < 4; nt++) acc[mt][nt] = mfma16(af, bfr[nt], acc[mt][nt]);
    }
    __syncthreads();
  }

  const int quad = lane >> 4;
#pragma unroll
  for (int mt = 0; mt < 4; mt++) {
#pragma unroll
    for (int r = 0; r < 4; r++) {
      int m = m0 + m0w + mt * 16 + quad * 4 + r;
      float bias = bkv[m];
#pragma unroll
      for (int nt = 0; nt < 4; nt++) {
        int n = n0 + n0w + nt * 16 + colL;
        float val = acc[mt][nt][r] + bias;
        if (m0 < C_) {
          Kf[((size_t)b * C_ + m) * N_ + n] = val;
        } else {
          Vb[((size_t)b * C_ + (m - C_)) * N_ + n] = f2bf(val);
        }
      }
    }
  }
}

// ---------------------------------------------------------------------------
// G3: k = softmax_N(Kf) -> kb bf16, one block per (b, c) row of 4096.
__global__ __launch_bounds__(256) void ksoftmax(const float* __restrict__ Kf,
                                                unsigned short* __restrict__ kb) {
  const int b = blockIdx.x >> 8, c = blockIdx.x & 255;
  const float* row = Kf + ((size_t)b * C_ + c) * N_;
  unsigned short* orow = kb + ((size_t)b * C_ + c) * N_;
  const int t = threadIdx.x, lane = t & 63, wv = t >> 6;
  __shared__ float red[8];

  float4 v[4];
  float mx = -1e30f;
#pragma unroll
  for (int i = 0; i < 4; i++) {
    v[i] = *(const float4*)&row[i * 1024 + t * 4];
    mx = fmaxf(fmaxf(fmaxf(mx, v[i].x), fmaxf(v[i].y, v[i].z)), v[i].w);
  }
#pragma unroll
  for (int o = 32; o > 0; o >>= 1) mx = fmaxf(mx, __shfl_down(mx, o));
  if (lane == 0) red[wv] = mx;
  __syncthreads();
  mx = fmaxf(fmaxf(red[0], red[1]), fmaxf(red[2], red[3]));

  float s = 0.f;
#pragma unroll
  for (int i = 0; i < 4; i++) {
    v[i].x = __expf(v[i].x - mx); v[i].y = __expf(v[i].y - mx);
    v[i].z = __expf(v[i].z - mx); v[i].w = __expf(v[i].w - mx);
    s += v[i].x + v[i].y + v[i].z + v[i].w;
  }
#pragma unroll
  for (int o = 32; o > 0; o >>= 1) s += __shfl_down(s, o);
  if (lane == 0) red[4 + wv] = s;
  __syncthreads();
  float inv = 1.0f / (red[4] + red[5] + red[6] + red[7]);
#pragma unroll
  for (int i = 0; i < 4; i++) {
    u16x4 o = (u16x4){f2bf(v[i].x * inv), f2bf(v[i].y * inv),
                      f2bf(v[i].z * inv), f2bf(v[i].w * inv)};
    *(u16x4*)&orow[i * 1024 + t * 4] = o;
  }
}

// ---------------------------------------------------------------------------
// G4: ctxp[s][b][c][d] = sum_{n in split s} kb[b][c][n] * Vb[b][d][n]  (NT)
// 128x64 tiles (512 blocks -> 2/CU), BK=64, register-prefetch pipeline.
__global__ __launch_bounds__(256) void ctx_part(
    const unsigned short* __restrict__ kb, const unsigned short* __restrict__ Vb,
    float* __restrict__ ctxp) {
  __shared__ unsigned short As[128][72];
  __shared__ unsigned short Bs[64][72];
  const int z = blockIdx.z, b = z >> 3, s = z & 7;
  const int m0 = blockIdx.y * 128, n0 = blockIdx.x * 64;
  const int tid = threadIdx.x, lane = tid & 63, w = tid >> 6;
  const int m0w = (w & 1) * 64, n0w = (w >> 1) * 32;
  const int colL = lane & 15, kq = lane >> 4;
  const unsigned short* Ab = kb + (size_t)b * C_ * N_;
  const unsigned short* Bb = Vb + (size_t)b * C_ * N_;

  f32x4 acc[4][2];
#pragma unroll
  for (int i = 0; i < 4; i++)
#pragma unroll
    for (int j = 0; j < 2; j++) acc[i][j] = (f32x4){0.f, 0.f, 0.f, 0.f};

  const int rs = tid >> 3, cs = (tid & 7) * 8;
  const int kbeg = s * (N_ / NSPLIT);

  u16x8 pa[4], pb[2];
#pragma unroll
  for (int i = 0; i < 4; i++) pa[i] = *(const u16x8*)&Ab[(size_t)(m0 + i * 32 + rs) * N_ + kbeg + cs];
#pragma unroll
  for (int i = 0; i < 2; i++) pb[i] = *(const u16x8*)&Bb[(size_t)(n0 + i * 32 + rs) * N_ + kbeg + cs];

  for (int kt = 0; kt < (N_ / NSPLIT) / 64; kt++) {
#pragma unroll
    for (int i = 0; i < 4; i++) *(u16x8*)&As[i * 32 + rs][cs] = pa[i];
#pragma unroll
    for (int i = 0; i < 2; i++) *(u16x8*)&Bs[i * 32 + rs][cs] = pb[i];
    __syncthreads();
    if (kt < (N_ / NSPLIT) / 64 - 1) {
      const int kc = kbeg + (kt + 1) * 64;
#pragma unroll
      for (int i = 0; i < 4; i++) pa[i] = *(const u16x8*)&Ab[(size_t)(m0 + i * 32 + rs) * N_ + kc + cs];
#pragma unroll
      for (int i = 0; i < 2; i++) pb[i] = *(const u16x8*)&Bb[(size_t)(n0 + i * 32 + rs) * N_ + kc + cs];
    }
#pragma unroll
    for (int ks = 0; ks < 2; ks++) {
      bf16x8 af[4], bfr[2];
#pragma unroll
      for (int mt = 0; mt < 4; mt++) af[mt] = *(const bf16x8*)&As[m0w + mt * 16 + colL][ks * 32 + kq * 8];
#pragma unroll
      for (int nt = 0; nt < 2; nt++) bfr[nt] = *(const bf16x8*)&Bs[n0w + nt * 16 + colL][ks * 32 + kq * 8];
#pragma unroll
      for (int mt = 0; mt < 4; mt++)
#pragma unroll
        for (int nt = 0; nt < 2; nt++) acc[mt][nt] = mfma16(af[mt], bfr[nt], acc[mt][nt]);
    }
    __syncthreads();
  }

  float* outp = ctxp + ((size_t)s * B_ + b) * C_ * C_;
  const int quad = lane >> 4;
#pragma unroll
  for (int mt = 0; mt < 4; mt++)
#pragma unroll
    for (int nt = 0; nt < 2; nt++)
#pragma unroll
      for (int r = 0; r < 4; r++) {
        int m = m0 + m0w + mt * 16 + quad * 4 + r;
        int n = n0 + n0w + nt * 16 + colL;
        outp[(size_t)m * C_ + n] = acc[mt][nt][r];
      }
}

// ---------------------------------------------------------------------------
// R: ctxs bf16 = sum over 8 split partials
__global__ __launch_bounds__(256) void ctx_reduce(const float* __restrict__ ctxp,
                                                  unsigned short* __restrict__ ctxs) {
  const size_t e = ((size_t)blockIdx.x * 256 + threadIdx.x) * 4;
  float4 a = {0.f, 0.f, 0.f, 0.f};
#pragma unroll
  for (int s = 0; s < NSPLIT; s++) {
    float4 v = *(const float4*)&ctxp[(size_t)s * B_ * C_ * C_ + e];
    a.x += v.x; a.y += v.y; a.z += v.z; a.w += v.w;
  }
  *(u16x4*)&ctxs[e] = (u16x4){f2bf(a.x), f2bf(a.y), f2bf(a.z), f2bf(a.w)};
}

// ---------------------------------------------------------------------------
// G5: ctx2[b] = wo @ ctxs[b]  (256x256x256, bf16 out), transposed B staging.
__global__ __launch_bounds__(256) void oproj(const float* __restrict__ wo,
                                             const unsigned short* __restrict__ ctxs,
                                             unsigned short* __restrict__ ctx2) {
  __shared__ unsigned short As[128][40];   // wo [m][k]
  __shared__ unsigned short Bs[128][40];   // ctxs^T [n][k]
  const int b = blockIdx.z;
  const int m0 = blockIdx.y * 128, n0 = blockIdx.x * 128;
  const int tid = threadIdx.x, lane = tid & 63, w = tid >> 6;
  const int m0w = (w >> 1) * 64, n0w = (w & 1) * 64;
  const int colL = lane & 15, kq = lane >> 4;
  const unsigned short* cb = ctxs + (size_t)b * C_ * C_;

  f32x4 acc[4][4];
#pragma unroll
  for (int i = 0; i < 4; i++)
#pragma unroll
    for (int j = 0; j < 4; j++) acc[i][j] = (f32x4){0.f, 0.f, 0.f, 0.f};

  const int kp = tid >> 4, nf2 = tid & 15;

  for (int kc = 0; kc < C_; kc += 32) {
    __syncthreads();
#pragma unroll
    for (int i = 0; i < 4; i++) {
      int r = i * 32 + (tid >> 3), c = (tid & 7) * 4;
      float4 v = *(const float4*)&wo[(size_t)(m0 + r) * C_ + kc + c];
      *(u16x4*)&As[r][c] = (u16x4){f2bf(v.x), f2bf(v.y), f2bf(v.z), f2bf(v.w)};
    }
#pragma unroll
    for (int i = 0; i < 2; i++) {
      u16x4 a0 = *(const u16x4*)&cb[(size_t)(kc + 2 * kp) * C_ + n0 + 4 * nf2 + 64 * i];
      u16x4 a1 = *(const u16x4*)&cb[(size_t)(kc + 2 * kp + 1) * C_ + n0 + 4 * nf2 + 64 * i];
#pragma unroll
      for (int j = 0; j < 4; j++)
        *(unsigned*)&Bs[4 * nf2 + 64 * i + j][2 * kp] = (unsigned)a0[j] | ((unsigned)a1[j] << 16);
    }
    __syncthreads();

    bf16x8 bfr[4];
#pragma unroll
    for (int nt = 0; nt < 4; nt++) bfr[nt] = *(const bf16x8*)&Bs[n0w + nt * 16 + colL][kq * 8];
#pragma unroll
    for (int mt = 0; mt < 4; mt++) {
      bf16x8 af = *(const bf16x8*)&As[m0w + mt * 16 + colL][kq * 8];
#pragma unroll
      for (int nt = 0; nt < 4; nt++) acc[mt][nt] = mfma16(af, bfr[nt], acc[mt][nt]);
    }
  }

  unsigned short* ob = ctx2 + (size_t)b * C_ * C_;
  const int quad = lane >> 4;
#pragma unroll
  for (int mt = 0; mt < 4; mt++)
#pragma unroll
    for (int nt = 0; nt < 4; nt++)
#pragma unroll
      for (int r = 0; r < 4; r++) {
        int m = m0 + m0w + mt * 16 + quad * 4 + r;
        int n = n0 + n0w + nt * 16 + colL;
        ob[(size_t)m * C_ + n] = f2bf(acc[mt][nt][r]);
      }
}

// ---------------------------------------------------------------------------
// G6: out[b][m][n] = sum_d ctx2[b][m][d] * qT[b][n][d] + bo[m]  (NT, fp32 out)
__global__ __launch_bounds__(256) void outgemm(const unsigned short* __restrict__ ctx2,
                                               const unsigned short* __restrict__ qT,
                                               const float* __restrict__ bo,
                                               float* __restrict__ out) {
  __shared__ unsigned short As[128][72];
  __shared__ unsigned short Bs[128][72];
  const int b = blockIdx.z;
  const int n0 = blockIdx.x * 128, m0 = blockIdx.y * 128;
  const int tid = threadIdx.x, lane = tid & 63, w = tid >> 6;
  const int m0w = (w >> 1) * 64, n0w = (w & 1) * 64;
  const int colL = lane & 15, kq = lane >> 4;
  const unsigned short* Ab = ctx2 + (size_t)b * C_ * C_;
  const unsigned short* Bb = qT + (size_t)b * N_ * C_;

  f32x4 acc[4][4];
#pragma unroll
  for (int i = 0; i < 4; i++)
#pragma unroll
    for (int j = 0; j < 4; j++) acc[i][j] = (f32x4){0.f, 0.f, 0.f, 0.f};

  const int rs = tid >> 3, cs = (tid & 7) * 8;

  u16x8 pa[4], pb[4];
#pragma unroll
  for (int i = 0; i < 4; i++) {
    pa[i] = *(const u16x8*)&Ab[(size_t)(m0 + i * 32 + rs) * C_ + cs];
    pb[i] = *(const u16x8*)&Bb[(size_t)(n0 + i * 32 + rs) * C_ + cs];
  }

  for (int kt = 0; kt < 4; kt++) {
#pragma unroll
    for (int i = 0; i < 4; i++) {
      *(u16x8*)&As[i * 32 + rs][cs] = pa[i];
      *(u16x8*)&Bs[i * 32 + rs][cs] = pb[i];
    }
    __syncthreads();
    if (kt < 3) {
      const int kc = (kt + 1) * 64;
#pragma unroll
      for (int i = 0; i < 4; i++) {
        pa[i] = *(const u16x8*)&Ab[(size_t)(m0 + i * 32 + rs) * C_ + kc + cs];
        pb[i] = *(const u16x8*)&Bb[(size_t)(n0 + i * 32 + rs) * C_ + kc + cs];
      }
    }
#pragma unroll
    for (int ks = 0; ks < 2; ks++) {
      bf16x8 af[4], bfr[4];
#pragma unroll
      for (int mt = 0; mt < 4; mt++) af[mt] = *(const bf16x8*)&As[m0w + mt * 16 + colL][ks * 32 + kq * 8];
#pragma unroll
      for (int nt = 0; nt < 4; nt++) bfr[nt] = *(const bf16x8*)&Bs[n0w + nt * 16 + colL][ks * 32 + kq * 8];
#pragma unroll
      for (int mt = 0; mt < 4; mt++)
#pragma unroll
        for (int nt = 0; nt < 4; nt++) acc[mt][nt] = mfma16(af[mt], bfr[nt], acc[mt][nt]);
    }
    __syncthreads();
  }

  float* ob = out + (size_t)b * C_ * N_;
  const int quad = lane >> 4;
#pragma unroll
  for (int mt = 0; mt < 4; mt++)
#pragma unroll
    for (int r = 0; r < 4; r++) {
      int m = m0 + m0w + mt * 16 + quad * 4 + r;
      float bias = bo[m];
#pragma unroll
      for (int nt = 0; nt < 4; nt++) {
        int n = n0 + n0w + nt * 16 + colL;
        ob[(size_t)m * N_ + n] = acc[mt][nt][r] + bias;
      }
    }
}

// ---------------------------------------------------------------------------
extern "C" void kernel_launch(void* const* d_in, const int* in_sizes, int n_in,
                              void* d_out, int out_size, void* d_ws, size_t ws_size,
                              hipStream_t stream) {
  const float* x     = (const float*)d_in[0];
  const float* cproj = (const float*)d_in[1];
  const float* wq    = (const float*)d_in[2];
  const float* bq    = (const float*)d_in[3];
  const float* wkv   = (const float*)d_in[4];
  const float* bkv   = (const float*)d_in[5];
  const float* wo    = (const float*)d_in[6];
  const float* bo    = (const float*)d_in[7];
  float* out = (float*)d_out;

  // workspace layout (~103 MB)
  unsigned short* qT   = (unsigned short*)d_ws;                       // B*N*C bf16
  float*          Kf   = (float*)(qT + (size_t)B_ * N_ * C_);         // B*C*N fp32
  unsigned short* Vb   = (unsigned short*)(Kf + (size_t)B_ * C_ * N_);// B*C*N bf16
  unsigned short* kb   = Vb + (size_t)B_ * C_ * N_;                   // B*C*N bf16
  float*          ctxp = (float*)(kb + (size_t)B_ * C_ * N_);         // 8*B*C*C fp32
  unsigned short* ctxs = (unsigned short*)(ctxp + (size_t)NSPLIT * B_ * C_ * C_);
  unsigned short* ctx2 = ctxs + (size_t)B_ * C_ * C_;

  qproj_softmax<<<dim3(N_ / 64, 1, B_), 256, 0, stream>>>(wq, x, bq, qT);
  kvproj<<<dim3(N_ / 128, KVC_ / 128, B_), 256, 0, stream>>>(wkv, cproj, bkv, Kf, Vb);
  ksoftmax<<<dim3(B_ * C_), 256, 0, stream>>>(Kf, kb);
  ctx_part<<<dim3(4, 2, B_ * NSPLIT), 256, 0, stream>>>(kb, Vb, ctxp);
  ctx_reduce<<<dim3(B_ * C_ * C_ / 1024), 256, 0, stream>>>(ctxp, ctxs);
  oproj<<<dim3(2, 2, B_), 256, 0, stream>>>(wo, ctxs, ctx2);
  outgemm<<<dim3(N_ / 128, 2, B_), 256, 0, stream>>>(ctx2, qT, bo, out);
}